// Round 8
// baseline (246.357 us; speedup 1.0000x reference)
//
#include <hip/hip_runtime.h>
#include <hip/hip_bf16.h>

typedef __attribute__((ext_vector_type(8))) short bf16x8;
typedef __attribute__((ext_vector_type(4))) float f32x4;
typedef unsigned short u16;
typedef unsigned int u32;

__device__ __forceinline__ u16 f2bf(float f) {
    u32 u = __float_as_uint(f);
    u = (u + 0x7FFFu + ((u >> 16) & 1u)) >> 16;
    return (u16)u;
}
__device__ __forceinline__ u32 pk2(float a, float b) {
    return (u32)f2bf(a) | ((u32)f2bf(b) << 16);
}
union B8 { u32 u[4]; bf16x8 v; };

// ---------- centers: cn = c/||c|| bf16, granule layout [b][kb24][dc4][k256][8] ----------
__global__ __launch_bounds__(256) void k_centers(const float* __restrict__ c, u16* __restrict__ cn) {
    int bid = blockIdx.x;                      // 512 blocks, 4 rows each
    int w = threadIdx.x >> 6, lane = threadIdx.x & 63;
    int row = (bid << 2) + w;                  // b*256 + k
    int b = row >> 8;
    __shared__ u16 rb[4][800];
    const float* src = c + (size_t)row * 768;
    float v[12]; float ss = 0.f;
#pragma unroll
    for (int j = 0; j < 12; ++j) { v[j] = src[lane + (j << 6)]; ss += v[j] * v[j]; }
#pragma unroll
    for (int m = 1; m < 64; m <<= 1) ss += __shfl_xor(ss, m, 64);
    float inv = 1.0f / sqrtf(ss);
#pragma unroll
    for (int j = 0; j < 12; ++j) rb[w][lane + (j << 6)] = f2bf(v[j] * inv);
    __syncthreads();
    int t = threadIdx.x;
    int k0 = (bid << 2) & 255;
#pragma unroll
    for (int p = 0; p < 2; ++p) {
        int idx = (p << 8) + t;
        if (idx < 384) {
            int g = idx >> 2, kr = idx & 3;
            uint4 val = *reinterpret_cast<const uint4*>(&rb[kr][g << 3]);
            int kb = g >> 2, dc = g & 3;
            size_t o = ((((size_t)(b * 24 + kb) << 2) + dc) << 8) + k0 + kr;
            *reinterpret_cast<uint4*>(cn + (o << 3)) = val;
        }
    }
}

// ---------- GEMM1: global-direct (gemm2-style), 64tok x 256K per block, no loop barriers ----------
__global__ __launch_bounds__(256, 3) void k_gemm1(const float* __restrict__ x, const u16* __restrict__ cn,
                                                  u16* __restrict__ probT, float* __restrict__ den) {
    const int bid = blockIdx.x;                // 1024 blocks
    const int b = bid & 7;                     // batch -> XCD (L2 holds this batch's cn)
    const int n0 = (bid >> 3) << 6;            // 64-token tile
    const int t = threadIdx.x;
    const int wave = t >> 6, lane = t & 63;
    const int lg = lane >> 4, lr = lane & 15;
    const int kq = wave << 6;                  // wave's K-quarter

    __shared__ u16 T[256][72];                 // 36,864 B transpose staging
    __shared__ float inv_s[64];
    __shared__ float ksum[4][64];
    __shared__ float denp[256];

    f32x4 acc[4][4];                           // [tf token-frag][kf K-frag]
#pragma unroll
    for (int tf = 0; tf < 4; ++tf)
#pragma unroll
        for (int kf = 0; kf < 4; ++kf) acc[tf][kf] = (f32x4){0.f, 0.f, 0.f, 0.f};

    const float* xb = x + ((size_t)b * 8192 + n0) * 768;
    const u16* cnb = cn + (size_t)b * 24 * 4 * 256 * 8;

    float sq[4] = {0.f, 0.f, 0.f, 0.f};

#pragma unroll 2
    for (int st = 0; st < 24; ++st) {          // d0 = st*32, lane handles d-slice lg*8
        bf16x8 bf[4];
#pragma unroll
        for (int kf = 0; kf < 4; ++kf)
            bf[kf] = *reinterpret_cast<const bf16x8*>(
                cnb + (((size_t)(st << 2) + lg) * 256 + kq + (kf << 4) + lr) * 8);
        bf16x8 af[4];
#pragma unroll
        for (int tf = 0; tf < 4; ++tf) {
            const float* p = xb + (size_t)((tf << 4) + lr) * 768 + (st << 5) + (lg << 3);
            float4 f0 = *reinterpret_cast<const float4*>(p);
            float4 f1 = *reinterpret_cast<const float4*>(p + 4);
            sq[tf] += f0.x*f0.x + f0.y*f0.y + f0.z*f0.z + f0.w*f0.w
                    + f1.x*f1.x + f1.y*f1.y + f1.z*f1.z + f1.w*f1.w;
            B8 a;
            a.u[0] = pk2(f0.x, f0.y); a.u[1] = pk2(f0.z, f0.w);
            a.u[2] = pk2(f1.x, f1.y); a.u[3] = pk2(f1.z, f1.w);
            af[tf] = a.v;
        }
#pragma unroll
        for (int tf = 0; tf < 4; ++tf)
#pragma unroll
            for (int kf = 0; kf < 4; ++kf)
                acc[tf][kf] = __builtin_amdgcn_mfma_f32_16x16x32_bf16(af[tf], bf[kf], acc[tf][kf], 0, 0, 0);
    }

    // token inverse-norms: reduce sq over lg groups (lanes lg*16+lr share token tf*16+lr)
#pragma unroll
    for (int tf = 0; tf < 4; ++tf) {
        sq[tf] += __shfl_xor(sq[tf], 16, 64);
        sq[tf] += __shfl_xor(sq[tf], 32, 64);
    }
    if (wave == 0 && lane < 16) {
#pragma unroll
        for (int tf = 0; tf < 4; ++tf) inv_s[(tf << 4) + lr] = 1.0f / sqrtf(sq[tf]);
    }
    __syncthreads();

    float iv[4][4];
#pragma unroll
    for (int tf = 0; tf < 4; ++tf)
#pragma unroll
        for (int r = 0; r < 4; ++r) iv[tf][r] = inv_s[(tf << 4) + (lg << 2) + r];

    // exp (logits bounded by |cos|<=~1: no max-subtract) + per-token sums over this wave's 64 K
    float rsum[4][4];
#pragma unroll
    for (int tf = 0; tf < 4; ++tf)
#pragma unroll
        for (int r = 0; r < 4; ++r) rsum[tf][r] = 0.f;
#pragma unroll
    for (int tf = 0; tf < 4; ++tf)
#pragma unroll
        for (int kf = 0; kf < 4; ++kf)
#pragma unroll
            for (int r = 0; r < 4; ++r) {
                float e = __expf(acc[tf][kf][r] * iv[tf][r]);
                acc[tf][kf][r] = e; rsum[tf][r] += e;
            }
#pragma unroll
    for (int tf = 0; tf < 4; ++tf)
#pragma unroll
        for (int r = 0; r < 4; ++r) {
#pragma unroll
            for (int m = 1; m < 16; m <<= 1) rsum[tf][r] += __shfl_xor(rsum[tf][r], m, 64);
        }
    if (lr == 0) {
#pragma unroll
        for (int tf = 0; tf < 4; ++tf)
#pragma unroll
            for (int r = 0; r < 4; ++r) ksum[wave][(tf << 4) + (lg << 2) + r] = rsum[tf][r];
    }
    __syncthreads();

    float rs[4][4];
#pragma unroll
    for (int tf = 0; tf < 4; ++tf)
#pragma unroll
        for (int r = 0; r < 4; ++r) {
            int i = (tf << 4) + (lg << 2) + r;
            rs[tf][r] = 1.0f / (ksum[0][i] + ksum[1][i] + ksum[2][i] + ksum[3][i]);
        }

    // prob, den K-column sums (wave owns kq..kq+63: plain LDS stores), transpose into T
    float dcol[4] = {0.f, 0.f, 0.f, 0.f};
#pragma unroll
    for (int tf = 0; tf < 4; ++tf)
#pragma unroll
        for (int kf = 0; kf < 4; ++kf)
#pragma unroll
            for (int r = 0; r < 4; ++r) {
                float p = acc[tf][kf][r] * rs[tf][r];
                acc[tf][kf][r] = p; dcol[kf] += p;
            }
#pragma unroll
    for (int kf = 0; kf < 4; ++kf) {
        dcol[kf] += __shfl_xor(dcol[kf], 16, 64);
        dcol[kf] += __shfl_xor(dcol[kf], 32, 64);
    }
    if (lg == 0) {
#pragma unroll
        for (int kf = 0; kf < 4; ++kf) denp[kq + (kf << 4) + lr] = dcol[kf];
    }
#pragma unroll
    for (int tf = 0; tf < 4; ++tf)
#pragma unroll
        for (int kf = 0; kf < 4; ++kf)
            *reinterpret_cast<ushort4*>(&T[kq + (kf << 4) + lr][(tf << 4) + (lg << 2)]) =
                make_ushort4(f2bf(acc[tf][kf][0]), f2bf(acc[tf][kf][1]),
                             f2bf(acc[tf][kf][2]), f2bf(acc[tf][kf][3]));
    __syncthreads();

    // coalesced writeout of probT tile [256][64]
    u16* pTb = probT + (size_t)b * 256 * 8192 + n0;
#pragma unroll
    for (int i = 0; i < 8; ++i) {
        int idx = (i << 8) + t;
        int row = idx >> 3, ch = idx & 7;
        *reinterpret_cast<uint4*>(pTb + (size_t)row * 8192 + (ch << 3)) =
            *reinterpret_cast<const uint4*>(&T[row][ch << 3]);
    }
    atomicAdd(&den[(b << 8) + t], denp[t]);
}

// ---------- GEMM2 (R2-proven body + XCD grouping): num_part[s][b][k][d] ----------
__global__ __launch_bounds__(256) void k_gemm2(const float* __restrict__ x, const u16* __restrict__ probT,
                                               float* __restrict__ num_part) {
    const int bid = blockIdx.x;                // 768 blocks
    const int xcd = bid & 7, slot = bid >> 3;
    const int orig = xcd * 96 + slot;
    const int dt = orig % 12, sb = orig / 12;  // 12 d-tiles of one (s,b) share an XCD
    const int s = sb >> 3, b = sb & 7;
    const int d0 = dt << 6;
    const int t = threadIdx.x;
    const int wave = t >> 6, lane = t & 63;
    const int lg = lane >> 4, lr = lane & 15;

    f32x4 acc[4][4];
#pragma unroll
    for (int m = 0; m < 4; ++m)
#pragma unroll
        for (int tt = 0; tt < 4; ++tt) acc[m][tt] = (f32x4){0.f, 0.f, 0.f, 0.f};

    const int n0 = s << 10;
    const u16* pA = probT + (size_t)b * 256 * 8192;
    const float* xB = x + (size_t)b * 8192 * 768;

    for (int kb = 0; kb < 32; ++kb) {
        int nbase = n0 + (kb << 5);
        bf16x8 a[4];
#pragma unroll
        for (int m = 0; m < 4; ++m) {
            int k = (wave << 6) + (m << 4) + lr;
            a[m] = *reinterpret_cast<const bf16x8*>(pA + (size_t)k * 8192 + nbase + (lg << 3));
        }
        const float* xr = xB + (size_t)(nbase + (lg << 3)) * 768 + d0 + lr;
        bf16x8 bb[4];
#pragma unroll
        for (int tt = 0; tt < 4; ++tt)
#pragma unroll
            for (int j = 0; j < 8; ++j) {
                float f = xr[(size_t)j * 768 + (tt << 4)];
                bb[tt][j] = (short)f2bf(f);
            }
#pragma unroll
        for (int m = 0; m < 4; ++m)
#pragma unroll
            for (int tt = 0; tt < 4; ++tt)
                acc[m][tt] = __builtin_amdgcn_mfma_f32_16x16x32_bf16(a[m], bb[tt], acc[m][tt], 0, 0, 0);
    }

    float* np = num_part + ((size_t)s * 8 + b) * 256 * 768;
#pragma unroll
    for (int m = 0; m < 4; ++m) {
        int kb_ = (wave << 6) + (m << 4) + (lg << 2);
#pragma unroll
        for (int reg = 0; reg < 4; ++reg)
#pragma unroll
            for (int tt = 0; tt < 4; ++tt)
                np[(size_t)(kb_ + reg) * 768 + d0 + (tt << 4) + lr] = acc[m][tt][reg];
    }
}

// ---------- finalize: out = sum_s num_part / (den + eps) ----------
__global__ __launch_bounds__(256) void k_final(const float* __restrict__ num_part, const float* __restrict__ den,
                                               float* __restrict__ out) {
    int i = blockIdx.x * 256 + threadIdx.x;
    float sum = 0.f;
#pragma unroll
    for (int ss = 0; ss < 8; ++ss) sum += num_part[(size_t)ss * 1572864 + i];
    out[i] = sum / (den[i / 768] + 1e-8f);
}

extern "C" void kernel_launch(void* const* d_in, const int* in_sizes, int n_in,
                              void* d_out, int out_size, void* d_ws, size_t ws_size,
                              hipStream_t stream) {
    const float* x = (const float*)d_in[0];
    const float* centers = (const float*)d_in[1];
    float* out = (float*)d_out;
    char* ws = (char*)d_ws;
    u16* cn       = (u16*)ws;                    //  3,145,728 B
    u16* probT    = (u16*)(ws + 3145728);        // 33,554,432 B
    float* den    = (float*)(ws + 36700160);     //      8,192 B
    float* numpt  = (float*)(ws + 36708352);     // 50,331,648 B  (total ~87 MB)

    hipMemsetAsync(den, 0, 8192, stream);
    k_centers<<<512, 256, 0, stream>>>(centers, cn);
    k_gemm1<<<1024, 256, 0, stream>>>(x, cn, probT, den);
    k_gemm2<<<768, 256, 0, stream>>>(x, probT, numpt);
    k_final<<<6144, 256, 0, stream>>>(numpt, den, out);
}

// Round 9
// 209.704 us; speedup vs baseline: 1.1748x; 1.1748x over previous
//
#include <hip/hip_runtime.h>
#include <hip/hip_bf16.h>

typedef __attribute__((ext_vector_type(8))) short bf16x8;
typedef __attribute__((ext_vector_type(4))) float f32x4;
typedef unsigned short u16;
typedef unsigned int u32;

__device__ __forceinline__ u16 f2bf(float f) {
    u32 u = __float_as_uint(f);
    u = (u + 0x7FFFu + ((u >> 16) & 1u)) >> 16;
    return (u16)u;
}

// ---------- centers: cn = c/||c|| bf16, granule layout [b][kb24][dc4][k256][8] ----------
__global__ __launch_bounds__(256) void k_centers(const float* __restrict__ c, u16* __restrict__ cn) {
    int bid = blockIdx.x;                      // 512 blocks, 4 rows each
    int w = threadIdx.x >> 6, lane = threadIdx.x & 63;
    int row = (bid << 2) + w;                  // b*256 + k
    int b = row >> 8;
    __shared__ u16 rb[4][800];
    const float* src = c + (size_t)row * 768;
    float v[12]; float ss = 0.f;
#pragma unroll
    for (int j = 0; j < 12; ++j) { v[j] = src[lane + (j << 6)]; ss += v[j] * v[j]; }
#pragma unroll
    for (int m = 1; m < 64; m <<= 1) ss += __shfl_xor(ss, m, 64);
    float inv = 1.0f / sqrtf(ss);
#pragma unroll
    for (int j = 0; j < 12; ++j) rb[w][lane + (j << 6)] = f2bf(v[j] * inv);
    __syncthreads();
    int t = threadIdx.x;
    int k0 = (bid << 2) & 255;
#pragma unroll
    for (int p = 0; p < 2; ++p) {
        int idx = (p << 8) + t;
        if (idx < 384) {
            int g = idx >> 2, kr = idx & 3;
            uint4 val = *reinterpret_cast<const uint4*>(&rb[kr][g << 3]);
            int kb = g >> 2, dc = g & 3;
            size_t o = ((((size_t)(b * 24 + kb) << 2) + dc) << 8) + k0 + kr;
            *reinterpret_cast<uint4*>(cn + (o << 3)) = val;
        }
    }
}

// ---------- prep: xbf = bf16(x), row-major, pure streaming copy (leaves xbf L3-resident) ----------
__global__ __launch_bounds__(256) void k_prep(const float* __restrict__ x, u16* __restrict__ xbf) {
    size_t i = (size_t)blockIdx.x * 256 + threadIdx.x;   // 6144 blocks
    const float4* xf = reinterpret_cast<const float4*>(x);
#pragma unroll
    for (int j = 0; j < 8; ++j) {
        size_t idx = i + (size_t)j * 1572864;
        float4 v = xf[idx];
        *reinterpret_cast<ushort4*>(xbf + (idx << 2)) =
            make_ushort4(f2bf(v.x), f2bf(v.y), f2bf(v.z), f2bf(v.w));
    }
}

// ---------- GEMM1: 64tok x 256K tile on warm bf16 x; reg-staged dbuf, issue-early/write-late ----------
__global__ __launch_bounds__(256, 3) void k_gemm1(const u16* __restrict__ xbf, const u16* __restrict__ cn,
                                                  u16* __restrict__ probT, float* __restrict__ den) {
    const int bid = blockIdx.x;                // 1024 blocks
    const int b = bid & 7;                     // batch -> XCD (cn slice + xbf stream L2 locality)
    const int n0 = (bid >> 3) << 6;            // 64-token tile
    const int t = threadIdx.x;
    const int wave = t >> 6, lane = t & 63;
    const int lg = lane >> 4, lr = lane & 15;
    const int kq = wave << 6;                  // wave's K-quarter

    __shared__ union {
        struct {
            u16 A[2][64][40];                  // 10,240 B (80B rows)
            u16 B[2][256][40];                 // 40,960 B (80B rows, dc-swizzled cols)
        } s;
        u16 T[256][72];                        // 36,864 B transpose staging
    } u;
    __shared__ float inv_s[64];
    __shared__ float ksum[4][64];

    f32x4 acc[4][4];                           // [tf token-frag][kf K-frag]
#pragma unroll
    for (int tf = 0; tf < 4; ++tf)
#pragma unroll
        for (int kf = 0; kf < 4; ++kf) acc[tf][kf] = (f32x4){0.f, 0.f, 0.f, 0.f};

    const u16* xb = xbf + ((size_t)b * 8192 + n0) * 768;
    const u16* cnb = cn + (size_t)b * 24 * 4 * 256 * 8;

    const int rowA = t >> 2;                   // staging: thread owns (row, 8-col granule)
    const int cgA = t & 3;
    const u16* apt = xb + (size_t)rowA * 768 + (cgA << 3);

    float sq = 0.f;
    uint4 la, lb0, lb1, lb2, lb3;

    auto issue = [&](int st) {
        la = *reinterpret_cast<const uint4*>(apt + (st << 5));
        const u16* src = cnb + ((size_t)st << 13);            // [dc4][k256][8] block, 16KB
        lb0 = *reinterpret_cast<const uint4*>(src + ((size_t)t << 3));
        lb1 = *reinterpret_cast<const uint4*>(src + ((size_t)(256 + t) << 3));
        lb2 = *reinterpret_cast<const uint4*>(src + ((size_t)(512 + t) << 3));
        lb3 = *reinterpret_cast<const uint4*>(src + ((size_t)(768 + t) << 3));
    };
    auto stage = [&](int buf) {
        // sum of squares from the staged bf16 values (row fixed per thread across iters)
        u32 ws[4] = {la.x, la.y, la.z, la.w};
#pragma unroll
        for (int j = 0; j < 4; ++j) {
            float lo = __uint_as_float(ws[j] << 16);
            float hi = __uint_as_float(ws[j] & 0xFFFF0000u);
            sq += lo * lo + hi * hi;
        }
        *reinterpret_cast<uint4*>(&u.s.A[buf][rowA][cgA << 3]) = la;
        *reinterpret_cast<uint4*>(&u.s.B[buf][t][((0 ^ (t & 3)) << 3)]) = lb0;
        *reinterpret_cast<uint4*>(&u.s.B[buf][t][((1 ^ (t & 3)) << 3)]) = lb1;
        *reinterpret_cast<uint4*>(&u.s.B[buf][t][((2 ^ (t & 3)) << 3)]) = lb2;
        *reinterpret_cast<uint4*>(&u.s.B[buf][t][((3 ^ (t & 3)) << 3)]) = lb3;
    };

    issue(0);
    stage(0);
    __syncthreads();

    for (int st = 0; st < 24; ++st) {
        int cur = st & 1, nxt = cur ^ 1;
        if (st < 23) issue(st + 1);            // loads fly across ds_read + MFMA phase
        bf16x8 a[4];
#pragma unroll
        for (int tf = 0; tf < 4; ++tf)
            a[tf] = *reinterpret_cast<const bf16x8*>(&u.s.A[cur][(tf << 4) + lr][lg << 3]);
#pragma unroll
        for (int kf = 0; kf < 4; ++kf) {
            bf16x8 bb = *reinterpret_cast<const bf16x8*>(
                &u.s.B[cur][kq + (kf << 4) + lr][(lg ^ (lr & 3)) << 3]);
#pragma unroll
            for (int tf = 0; tf < 4; ++tf)
                acc[tf][kf] = __builtin_amdgcn_mfma_f32_16x16x32_bf16(a[tf], bb, acc[tf][kf], 0, 0, 0);
        }
        if (st < 23) stage(nxt);               // ds_write waits only its own regs
        __syncthreads();
    }

    // token inverse-norms: thread quad (t&3) shares rowA
    sq += __shfl_xor(sq, 1, 64);
    sq += __shfl_xor(sq, 2, 64);
    if ((t & 3) == 0) inv_s[rowA] = 1.0f / sqrtf(sq);
    __syncthreads();

    float iv[4][4];
#pragma unroll
    for (int tf = 0; tf < 4; ++tf)
#pragma unroll
        for (int r = 0; r < 4; ++r) iv[tf][r] = inv_s[(tf << 4) + (lg << 2) + r];

    // exp (logits bounded by |cos|<=~1: no max-subtract) + per-token sums over this wave's 64 K
    float rsum[4][4];
#pragma unroll
    for (int tf = 0; tf < 4; ++tf)
#pragma unroll
        for (int r = 0; r < 4; ++r) rsum[tf][r] = 0.f;
#pragma unroll
    for (int tf = 0; tf < 4; ++tf)
#pragma unroll
        for (int kf = 0; kf < 4; ++kf)
#pragma unroll
            for (int r = 0; r < 4; ++r) {
                float e = __expf(acc[tf][kf][r] * iv[tf][r]);
                acc[tf][kf][r] = e; rsum[tf][r] += e;
            }
#pragma unroll
    for (int tf = 0; tf < 4; ++tf)
#pragma unroll
        for (int r = 0; r < 4; ++r) {
#pragma unroll
            for (int m = 1; m < 16; m <<= 1) rsum[tf][r] += __shfl_xor(rsum[tf][r], m, 64);
        }
    if (lr == 0) {
#pragma unroll
        for (int tf = 0; tf < 4; ++tf)
#pragma unroll
            for (int r = 0; r < 4; ++r) ksum[wave][(tf << 4) + (lg << 2) + r] = rsum[tf][r];
    }
    __syncthreads();

    float rs[4][4];
#pragma unroll
    for (int tf = 0; tf < 4; ++tf)
#pragma unroll
        for (int r = 0; r < 4; ++r) {
            int i = (tf << 4) + (lg << 2) + r;
            rs[tf][r] = 1.0f / (ksum[0][i] + ksum[1][i] + ksum[2][i] + ksum[3][i]);
        }

    // prob, den K-column sums (direct global atomics), transpose into T
    float dcol[4] = {0.f, 0.f, 0.f, 0.f};
#pragma unroll
    for (int tf = 0; tf < 4; ++tf)
#pragma unroll
        for (int kf = 0; kf < 4; ++kf)
#pragma unroll
            for (int r = 0; r < 4; ++r) {
                float p = acc[tf][kf][r] * rs[tf][r];
                acc[tf][kf][r] = p; dcol[kf] += p;
            }
#pragma unroll
    for (int kf = 0; kf < 4; ++kf) {
        dcol[kf] += __shfl_xor(dcol[kf], 16, 64);
        dcol[kf] += __shfl_xor(dcol[kf], 32, 64);
    }
    if (lg == 0) {
#pragma unroll
        for (int kf = 0; kf < 4; ++kf) atomicAdd(&den[(b << 8) + kq + (kf << 4) + lr], dcol[kf]);
    }
#pragma unroll
    for (int tf = 0; tf < 4; ++tf)
#pragma unroll
        for (int kf = 0; kf < 4; ++kf)
            *reinterpret_cast<ushort4*>(&u.T[kq + (kf << 4) + lr][(tf << 4) + (lg << 2)]) =
                make_ushort4(f2bf(acc[tf][kf][0]), f2bf(acc[tf][kf][1]),
                             f2bf(acc[tf][kf][2]), f2bf(acc[tf][kf][3]));
    __syncthreads();

    // coalesced writeout of probT tile [256][64]
    u16* pTb = probT + (size_t)b * 256 * 8192 + n0;
#pragma unroll
    for (int i = 0; i < 8; ++i) {
        int idx = (i << 8) + t;
        int row = idx >> 3, ch = idx & 7;
        *reinterpret_cast<uint4*>(pTb + (size_t)row * 8192 + (ch << 3)) =
            *reinterpret_cast<const uint4*>(&u.T[row][ch << 3]);
    }
}

// ---------- GEMM2: num_part[s][b][k][d] from probT (warm) and xbf (warm bf16) ----------
__global__ __launch_bounds__(256) void k_gemm2(const u16* __restrict__ xbf, const u16* __restrict__ probT,
                                               float* __restrict__ num_part) {
    const int bid = blockIdx.x;                // 768 blocks
    const int xcd = bid & 7, slot = bid >> 3;
    const int orig = xcd * 96 + slot;
    const int dt = orig % 12, sb = orig / 12;  // 12 d-tiles of one (s,b) share an XCD
    const int s = sb >> 3, b = sb & 7;
    const int d0 = dt << 6;
    const int t = threadIdx.x;
    const int wave = t >> 6, lane = t & 63;
    const int lg = lane >> 4, lr = lane & 15;

    f32x4 acc[4][4];
#pragma unroll
    for (int m = 0; m < 4; ++m)
#pragma unroll
        for (int tt = 0; tt < 4; ++tt) acc[m][tt] = (f32x4){0.f, 0.f, 0.f, 0.f};

    const int n0 = s << 10;
    const u16* pA = probT + (size_t)b * 256 * 8192;
    const u16* xB = xbf + (size_t)b * 8192 * 768;

    for (int kb = 0; kb < 32; ++kb) {
        int nbase = n0 + (kb << 5);
        bf16x8 a[4];
#pragma unroll
        for (int m = 0; m < 4; ++m) {
            int k = (wave << 6) + (m << 4) + lr;
            a[m] = *reinterpret_cast<const bf16x8*>(pA + (size_t)k * 8192 + nbase + (lg << 3));
        }
        const u16* xr = xB + (size_t)(nbase + (lg << 3)) * 768 + d0 + lr;
        bf16x8 bb[4];
#pragma unroll
        for (int tt = 0; tt < 4; ++tt)
#pragma unroll
            for (int j = 0; j < 8; ++j)
                bb[tt][j] = (short)xr[(size_t)j * 768 + (tt << 4)];
#pragma unroll
        for (int m = 0; m < 4; ++m)
#pragma unroll
            for (int tt = 0; tt < 4; ++tt)
                acc[m][tt] = __builtin_amdgcn_mfma_f32_16x16x32_bf16(a[m], bb[tt], acc[m][tt], 0, 0, 0);
    }

    float* np = num_part + ((size_t)s * 8 + b) * 256 * 768;
#pragma unroll
    for (int m = 0; m < 4; ++m) {
        int kb_ = (wave << 6) + (m << 4) + (lg << 2);
#pragma unroll
        for (int reg = 0; reg < 4; ++reg)
#pragma unroll
            for (int tt = 0; tt < 4; ++tt)
                np[(size_t)(kb_ + reg) * 768 + d0 + (tt << 4) + lr] = acc[m][tt][reg];
    }
}

// ---------- finalize: out = sum_s num_part / (den + eps) ----------
__global__ __launch_bounds__(256) void k_final(const float* __restrict__ num_part, const float* __restrict__ den,
                                               float* __restrict__ out) {
    int i = blockIdx.x * 256 + threadIdx.x;
    float sum = 0.f;
#pragma unroll
    for (int ss = 0; ss < 8; ++ss) sum += num_part[(size_t)ss * 1572864 + i];
    out[i] = sum / (den[i / 768] + 1e-8f);
}

extern "C" void kernel_launch(void* const* d_in, const int* in_sizes, int n_in,
                              void* d_out, int out_size, void* d_ws, size_t ws_size,
                              hipStream_t stream) {
    const float* x = (const float*)d_in[0];
    const float* centers = (const float*)d_in[1];
    float* out = (float*)d_out;
    char* ws = (char*)d_ws;
    u16* cn       = (u16*)ws;                    //   3,145,728 B
    u16* probT    = (u16*)(ws + 3145728);        //  33,554,432 B
    float* den    = (float*)(ws + 36700160);     //       8,192 B
    u16* xbf      = (u16*)(ws + 36708352);       // 100,663,296 B
    float* numpt  = (float*)(ws + 137371648);    //  50,331,648 B  (total ~188 MB)

    hipMemsetAsync(den, 0, 8192, stream);
    k_centers<<<512, 256, 0, stream>>>(centers, cn);
    k_prep<<<6144, 256, 0, stream>>>(x, xbf);
    k_gemm1<<<1024, 256, 0, stream>>>(xbf, cn, probT, den);
    k_gemm2<<<768, 256, 0, stream>>>(xbf, probT, numpt);
    k_final<<<6144, 256, 0, stream>>>(numpt, den, out);
}